// Round 7
// baseline (11050.983 us; speedup 1.0000x reference)
//
#include <hip/hip_runtime.h>
#include <math.h>

#define NB   256   // one block per CU — co-resident (132 KB LDS forces 1/CU)
#define NT   512
#define Bsz  256
#define Ssz  256
#define Hsz  512
#define Osz  512
#define RSTRIDE 1032   // LDS row stride in floats (1024 + 8 pad: rotates banks/row)

#define AGENT __HIP_MEMORY_SCOPE_AGENT
#define RLX   __ATOMIC_RELAXED
typedef unsigned long long ull_t;

// Dynamic LDS: 32 rows x RSTRIDE floats (132 KB), PLAIN ROW-MAJOR [emb(512)|h(512)].
// JB4 GEMM: wave w owns 4 cols (jc0 = w*4); lane ks (0..63) owns K-chunks
// k = i*256 + ks*4. Per (i,r) ds_read_b128: 64 lanes x 16 B contiguous (1 KB)
// = conflict-free; each read feeds 4 columns (half the LDS instructions of R6's
// JB2). Weights use the same k map: W + col*1024 + ks*4 + i*256 — per-wave
// coalesced 1 KB, L1/L2-resident.
extern __shared__ float sx[];

// Stage the h-half of all 32 rows from global src (agent-scope loads bypass
// L1/L2 -> no stale data). 16 lanes/row x 8 float4; batched 2 rounds of 4.
__device__ __forceinline__ void stage_h(const float* src, int b0, int tid) {
  const int r = tid >> 4, l = tid & 15;
  const float* rowp = src + (((size_t)(b0 + r)) << 9);
  #pragma unroll
  for (int hh = 0; hh < 2; ++hh) {
    ull_t v0[4], v1[4];
    #pragma unroll
    for (int m = 0; m < 4; ++m) {
      const int g = ((hh << 2) + m) * 16 + l;        // float4 idx 0..127
      v0[m] = __hip_atomic_load((const ull_t*)(rowp + (g << 2)), RLX, AGENT);
      v1[m] = __hip_atomic_load((const ull_t*)(rowp + (g << 2) + 2), RLX, AGENT);
    }
    #pragma unroll
    for (int m = 0; m < 4; ++m) {
      const int g = ((hh << 2) + m) * 16 + l;
      float* d = &sx[r * RSTRIDE + 512 + (g << 2)];
      *(ull_t*)d       = v0[m];
      *(ull_t*)(d + 2) = v1[m];
    }
  }
}

// Per-batch-group barrier: the 8 bgrps are fully independent recurrences,
// so sync only the 32 partner blocks.
__device__ __forceinline__ void group_barrier(unsigned* flags, unsigned& target,
                                              int gbase, int tid, int bid) {
  ++target;
  __builtin_amdgcn_s_waitcnt(0);
  __syncthreads();
  __atomic_signal_fence(__ATOMIC_SEQ_CST);
  if (tid == 0)
    __hip_atomic_store(&flags[bid], target, RLX, AGENT);
  if (tid < 32) {
    while (__hip_atomic_load(&flags[gbase + tid], RLX, AGENT) < target)
      __builtin_amdgcn_s_sleep(2);
  }
  __atomic_signal_fence(__ATOMIC_SEQ_CST);
  __syncthreads();
}

// Merged 4-column butterfly reduce over 64 K-lanes: lane ks ends up holding
// the full sum of column (ks&3). 7 shuffles for 4 columns.
__device__ __forceinline__ float reduce4(float a0, float a1, float a2, float a3,
                                         int ks) {
  float u01 = (ks & 1) ? a1 : a0;
  float v01 = (ks & 1) ? a0 : a1;
  u01 += __shfl_xor(v01, 1);
  float u23 = (ks & 1) ? a3 : a2;
  float v23 = (ks & 1) ? a2 : a3;
  u23 += __shfl_xor(v23, 1);
  float u = (ks & 2) ? u23 : u01;
  float v = (ks & 2) ? u01 : u23;
  u += __shfl_xor(v, 2);
  u += __shfl_xor(u, 4);
  u += __shfl_xor(u, 8);
  u += __shfl_xor(u, 16);
  u += __shfl_xor(u, 32);
  return u;
}

__global__ __attribute__((amdgpu_flat_work_group_size(NT, NT),
                          amdgpu_waves_per_eu(2, 2)))
void gru_persistent(
    const int* __restrict__ x, const float* __restrict__ emb,
    const float* __restrict__ Wg, const float* __restrict__ bgp,
    const float* __restrict__ Wh, const float* __restrict__ bhp,
    const float* __restrict__ Wo, const float* __restrict__ bop,
    float* __restrict__ out, float* __restrict__ ws)
{
  const int tid  = threadIdx.x;
  const int bid  = blockIdx.x;
  const int bgrp = bid >> 5;          // 8 row-groups of 32 batch rows
  const int jg   = bid & 31;          // 32 column-slice groups
  const int gbase = bgrp << 5;
  const int b0   = bgrp << 5;
  const int wv   = tid >> 6;          // wave id (0..7) = col-quad
  const int ks   = tid & 63;          // K lane (4 floats per i-chunk)
  const bool is_cand = (jg < 16);
  const int j0a = jg << 5;            // phase-A gate col base (0..1023)
  const int j0b = (jg & 15) << 5;     // phase-B col base (0..511)
  const int jc0 = wv << 2;            // first of this wave's 4 columns

  unsigned* flags = (unsigned*)ws;    // [256] barrier flags (memset 0)
  float* H0 = ws + 256;               // [256][512] h ping (memset 0 = h0)
  float* H1 = H0 + Bsz * Hsz;
  float* RH = H1 + Bsz * Hsz;
  float* ys = out + Bsz * Hsz;

  __shared__ float szv[32][32];
  __shared__ float shv[32][32];
  __shared__ float sWB[32][32];       // staging for coalesced RH / Hn writes
  __shared__ int   sIdxN[32];         // next step's token index per row

  // ---- persistent register weights: k = i*256 + ks*4, 4 cols/wave ----
  float4 wa[4][4];
  {
    const float* p = Wg + (size_t)(j0a + jc0) * 1024 + (ks << 2);
    #pragma unroll
    for (int c = 0; c < 4; ++c)
      #pragma unroll
      for (int i = 0; i < 4; ++i)
        wa[c][i] = *(const float4*)(p + c * 1024 + (i << 8));
  }
  float4 wb[4][4];
  if (is_cand) {
    const float* p = Wh + (size_t)(j0b + jc0) * 1024 + (ks << 2);
    #pragma unroll
    for (int c = 0; c < 4; ++c)
      #pragma unroll
      for (int i = 0; i < 4; ++i)
        wb[c][i] = *(const float4*)(p + c * 1024 + (i << 8));
  } else {
    const float* p = Wo + (size_t)(j0b + jc0) * 512 + (ks << 2);
    #pragma unroll
    for (int c = 0; c < 4; ++c)
      #pragma unroll
      for (int i = 0; i < 2; ++i)
        wb[c][i] = *(const float4*)(p + c * 512 + (i << 8));
  }
  const float bA = bgp[j0a + jc0 + (ks & 3)];
  const float bB = is_cand ? bhp[j0b + jc0 + (ks & 3)] : bop[j0b + jc0 + (ks & 3)];

  // ---- xe prefetch: thread (pr,pl) owns 8 float4 of row pr's emb ----
  const int pr = tid >> 4, pl = tid & 15;
  float4 xv[8];

  if (tid < 32) sIdxN[tid] = x[(b0 + tid) * Ssz];
  __syncthreads();
  {
    const float4* ep = (const float4*)(emb + (size_t)sIdxN[pr] * Hsz);
    #pragma unroll
    for (int m = 0; m < 8; ++m) xv[m] = ep[(m << 4) + pl];
  }

  const int bx = ks << 2;
  unsigned target = 0;

  for (int t = 0; t < Ssz; ++t) {
    float* Hc = (t & 1) ? H1 : H0;
    float* Hn = (t & 1) ? H0 : H1;

    // ---- commit prefetched emb half (row-major, contiguous 256 B runs) ----
    #pragma unroll
    for (int m = 0; m < 8; ++m)
      *(float4*)&sx[pr * RSTRIDE + (((m << 4) + pl) << 2)] = xv[m];
    // ---- stage h half via LLC ----
    stage_h(Hc, b0, tid);
    __syncthreads();

    // next step's token indices (consumed at the mid barrier)
    if (tid < 32)
      sIdxN[tid] = x[(b0 + tid) * Ssz + ((t + 1 < Ssz) ? t + 1 : t)];

    // ---------------- Phase A: gates (K=1024, 4 cols/wave) ----------------
    {
      #pragma unroll 2
      for (int r = 0; r < 32; ++r) {
        const float* xp = &sx[r * RSTRIDE + bx];
        float4 acc0 = {0.f,0.f,0.f,0.f}, acc1 = {0.f,0.f,0.f,0.f};
        float4 acc2 = {0.f,0.f,0.f,0.f}, acc3 = {0.f,0.f,0.f,0.f};
        #pragma unroll
        for (int i = 0; i < 4; ++i) {
          const float4 xq = *(const float4*)(xp + (i << 8));
          acc0.x += wa[0][i].x * xq.x; acc0.y += wa[0][i].y * xq.y;
          acc0.z += wa[0][i].z * xq.z; acc0.w += wa[0][i].w * xq.w;
          acc1.x += wa[1][i].x * xq.x; acc1.y += wa[1][i].y * xq.y;
          acc1.z += wa[1][i].z * xq.z; acc1.w += wa[1][i].w * xq.w;
          acc2.x += wa[2][i].x * xq.x; acc2.y += wa[2][i].y * xq.y;
          acc2.z += wa[2][i].z * xq.z; acc2.w += wa[2][i].w * xq.w;
          acc3.x += wa[3][i].x * xq.x; acc3.y += wa[3][i].y * xq.y;
          acc3.z += wa[3][i].z * xq.z; acc3.w += wa[3][i].w * xq.w;
        }
        const float u = reduce4((acc0.x + acc0.y) + (acc0.z + acc0.w),
                                (acc1.x + acc1.y) + (acc1.z + acc1.w),
                                (acc2.x + acc2.y) + (acc2.z + acc2.w),
                                (acc3.x + acc3.y) + (acc3.z + acc3.w), ks);
        if (ks < 4) {
          const int jj = jc0 + ks;
          const float s = 1.f / (1.f + expf(-(u + bA)));
          if (is_cand) {
            szv[r][jj] = s;
            shv[r][jj] = sx[r * RSTRIDE + 512 + j0b + jj];
          } else {
            const int hj = j0a + jj - 512;
            sWB[r][jj] = s * sx[r * RSTRIDE + 512 + hj];   // stage r*h
          }
        }
      }
    }

    // ---- coalesced RH write (out-role): dense 8 B agent stores ----
    __syncthreads();
    if (!is_cand) {
      const int row = tid >> 4, q = tid & 15;
      __hip_atomic_store(
          (ull_t*)(RH + (((size_t)(b0 + row)) << 9) + (j0a - 512) + (q << 1)),
          *(const ull_t*)&sWB[row][q << 1], RLX, AGENT);
    }

    // -------- mid barrier (per-bgrp) with xe-prefetch in the window --------
    {
      ++target;
      __builtin_amdgcn_s_waitcnt(0);
      __syncthreads();                 // sIdxN visible to all waves
      __atomic_signal_fence(__ATOMIC_SEQ_CST);
      if (tid == 0)
        __hip_atomic_store(&flags[bid], target, RLX, AGENT);
      {
        const float4* ep = (const float4*)(emb + (size_t)sIdxN[pr] * Hsz);
        #pragma unroll
        for (int m = 0; m < 8; ++m) xv[m] = ep[(m << 4) + pl];
      }
      if (tid < 32) {
        while (__hip_atomic_load(&flags[gbase + tid], RLX, AGENT) < target)
          __builtin_amdgcn_s_sleep(2);
      }
      __atomic_signal_fence(__ATOMIC_SEQ_CST);
      __syncthreads();
    }

    // ---------------- Phase B ----------------
    if (is_cand) {
      stage_h(RH, b0, tid);            // overwrite h-half with r*h
      __syncthreads();
      #pragma unroll 2
      for (int r = 0; r < 32; ++r) {
        const float* xp = &sx[r * RSTRIDE + bx];
        float4 acc0 = {0.f,0.f,0.f,0.f}, acc1 = {0.f,0.f,0.f,0.f};
        float4 acc2 = {0.f,0.f,0.f,0.f}, acc3 = {0.f,0.f,0.f,0.f};
        #pragma unroll
        for (int i = 0; i < 4; ++i) {
          const float4 xq = *(const float4*)(xp + (i << 8));
          acc0.x += wb[0][i].x * xq.x; acc0.y += wb[0][i].y * xq.y;
          acc0.z += wb[0][i].z * xq.z; acc0.w += wb[0][i].w * xq.w;
          acc1.x += wb[1][i].x * xq.x; acc1.y += wb[1][i].y * xq.y;
          acc1.z += wb[1][i].z * xq.z; acc1.w += wb[1][i].w * xq.w;
          acc2.x += wb[2][i].x * xq.x; acc2.y += wb[2][i].y * xq.y;
          acc2.z += wb[2][i].z * xq.z; acc2.w += wb[2][i].w * xq.w;
          acc3.x += wb[3][i].x * xq.x; acc3.y += wb[3][i].y * xq.y;
          acc3.z += wb[3][i].z * xq.z; acc3.w += wb[3][i].w * xq.w;
        }
        const float u = reduce4((acc0.x + acc0.y) + (acc0.z + acc0.w),
                                (acc1.x + acc1.y) + (acc1.z + acc1.w),
                                (acc2.x + acc2.y) + (acc2.z + acc2.w),
                                (acc3.x + acc3.y) + (acc3.z + acc3.w), ks);
        if (ks < 4) {
          const int jj = jc0 + ks;
          const float cd = tanhf(u + bB);
          const float zv = szv[r][jj], hv = shv[r][jj];
          sWB[r][jj] = (1.f - zv) * hv + zv * cd;      // stage h_new
        }
      }
      __syncthreads();
      {  // coalesced Hn write: dense 8 B agent stores
        const int row = tid >> 4, q = tid & 15;
        const ull_t v = *(const ull_t*)&sWB[row][q << 1];
        __hip_atomic_store(
            (ull_t*)(Hn + (((size_t)(b0 + row)) << 9) + j0b + (q << 1)),
            v, RLX, AGENT);
        if (t == Ssz - 1)
          *(ull_t*)(out + (((b0 + row)) << 9) + j0b + (q << 1)) = v;
      }
    } else if (t > 0) {
      const int by = 512 + bx;
      #pragma unroll 2
      for (int r = 0; r < 32; ++r) {
        const float* xp = &sx[r * RSTRIDE + by];
        float4 acc0 = {0.f,0.f,0.f,0.f}, acc1 = {0.f,0.f,0.f,0.f};
        float4 acc2 = {0.f,0.f,0.f,0.f}, acc3 = {0.f,0.f,0.f,0.f};
        #pragma unroll
        for (int i = 0; i < 2; ++i) {
          const float4 xq = *(const float4*)(xp + (i << 8));
          acc0.x += wb[0][i].x * xq.x; acc0.y += wb[0][i].y * xq.y;
          acc0.z += wb[0][i].z * xq.z; acc0.w += wb[0][i].w * xq.w;
          acc1.x += wb[1][i].x * xq.x; acc1.y += wb[1][i].y * xq.y;
          acc1.z += wb[1][i].z * xq.z; acc1.w += wb[1][i].w * xq.w;
          acc2.x += wb[2][i].x * xq.x; acc2.y += wb[2][i].y * xq.y;
          acc2.z += wb[2][i].z * xq.z; acc2.w += wb[2][i].w * xq.w;
          acc3.x += wb[3][i].x * xq.x; acc3.y += wb[3][i].y * xq.y;
          acc3.z += wb[3][i].z * xq.z; acc3.w += wb[3][i].w * xq.w;
        }
        const float u = reduce4((acc0.x + acc0.y) + (acc0.z + acc0.w),
                                (acc1.x + acc1.y) + (acc1.z + acc1.w),
                                (acc2.x + acc2.y) + (acc2.z + acc2.w),
                                (acc3.x + acc3.y) + (acc3.z + acc3.w), ks);
        if (ks < 4)
          ys[((size_t)(b0 + r) * Ssz + (t - 1)) * Osz + (j0b + jc0 + ks)] = u + bB;
      }
    }

    group_barrier(flags, target, gbase, tid, bid);
  }

  // ---- tail: y_{S-1} from h_S (Ssz even -> h_S in H0) ----
  if (!is_cand) {
    stage_h(H0, b0, tid);
    __syncthreads();
    const int by = 512 + bx;
    #pragma unroll 2
    for (int r = 0; r < 32; ++r) {
      const float* xp = &sx[r * RSTRIDE + by];
      float4 acc0 = {0.f,0.f,0.f,0.f}, acc1 = {0.f,0.f,0.f,0.f};
      float4 acc2 = {0.f,0.f,0.f,0.f}, acc3 = {0.f,0.f,0.f,0.f};
      #pragma unroll
      for (int i = 0; i < 2; ++i) {
        const float4 xq = *(const float4*)(xp + (i << 8));
        acc0.x += wb[0][i].x * xq.x; acc0.y += wb[0][i].y * xq.y;
        acc0.z += wb[0][i].z * xq.z; acc0.w += wb[0][i].w * xq.w;
        acc1.x += wb[1][i].x * xq.x; acc1.y += wb[1][i].y * xq.y;
        acc1.z += wb[1][i].z * xq.z; acc1.w += wb[1][i].w * xq.w;
        acc2.x += wb[2][i].x * xq.x; acc2.y += wb[2][i].y * xq.y;
        acc2.z += wb[2][i].z * xq.z; acc2.w += wb[2][i].w * xq.w;
        acc3.x += wb[3][i].x * xq.x; acc3.y += wb[3][i].y * xq.y;
        acc3.z += wb[3][i].z * xq.z; acc3.w += wb[3][i].w * xq.w;
      }
      const float u = reduce4((acc0.x + acc0.y) + (acc0.z + acc0.w),
                              (acc1.x + acc1.y) + (acc1.z + acc1.w),
                              (acc2.x + acc2.y) + (acc2.z + acc2.w),
                              (acc3.x + acc3.y) + (acc3.z + acc3.w), ks);
      if (ks < 4)
        ys[((size_t)(b0 + r) * Ssz + (Ssz - 1)) * Osz + (j0b + jc0 + ks)] = u + bB;
    }
  }
}

extern "C" void kernel_launch(void* const* d_in, const int* in_sizes, int n_in,
                              void* d_out, int out_size, void* d_ws, size_t ws_size,
                              hipStream_t stream) {
  const int*   x   = (const int*)  d_in[0];
  const float* emb = (const float*)d_in[1];
  const float* Wg  = (const float*)d_in[2];
  const float* bg  = (const float*)d_in[3];
  const float* Wh  = (const float*)d_in[4];
  const float* bh  = (const float*)d_in[5];
  const float* Wo  = (const float*)d_in[6];
  const float* bo  = (const float*)d_in[7];
  float* out = (float*)d_out;
  float* ws  = (float*)d_ws;

  const int dynLds = 32 * RSTRIDE * 4;   // 132,096 B -> 1 block/CU
  hipFuncSetAttribute((const void*)gru_persistent,
                      hipFuncAttributeMaxDynamicSharedMemorySize, dynLds);

  // Zero barrier flags (256 u32) + H0 (= h0). ws re-poisoned every launch.
  hipMemsetAsync(d_ws, 0, (256 + Bsz * Hsz) * sizeof(float), stream);

  gru_persistent<<<NB, NT, dynLds, stream>>>(x, emb, Wg, bg, Wh, bh, Wo, bo, out, ws);
}